// Round 5
// baseline (114.853 us; speedup 1.0000x reference)
//
#include <hip/hip_runtime.h>

using bf16x8 = __attribute__((ext_vector_type(8))) short;
using u16x8  = __attribute__((ext_vector_type(8))) unsigned short;
using f32x4  = __attribute__((ext_vector_type(4))) float;

static constexpr int S  = 2048;
static constexpr int D  = 64;
static constexpr int TQ = 64;
static constexpr float QSCALE = 0.18033688f; // log2(e)/8 : exp2(dot) == exp(dot/8)

__device__ __forceinline__ unsigned short bf16_rne(float x) {
    unsigned u = __builtin_bit_cast(unsigned, x);
    u += 0x7FFFu + ((u >> 16) & 1u);
    return (unsigned short)(u >> 16);
}
__device__ __forceinline__ float bf16_f32(unsigned short h) {
    unsigned u = ((unsigned)h) << 16;
    return __builtin_bit_cast(float, u);
}
__device__ __forceinline__ f32x4 mfma16(bf16x8 a, bf16x8 b, f32x4 c) {
    return __builtin_amdgcn_mfma_f32_16x16x32_bf16(a, b, c, 0, 0, 0);
}
__device__ __forceinline__ bf16x8 cvt8(float4 a, float4 b) {
    u16x8 r;
    r[0] = bf16_rne(a.x); r[1] = bf16_rne(a.y); r[2] = bf16_rne(a.z); r[3] = bf16_rne(a.w);
    r[4] = bf16_rne(b.x); r[5] = bf16_rne(b.y); r[6] = bf16_rne(b.z); r[7] = bf16_rne(b.w);
    return __builtin_bit_cast(bf16x8, r);
}

// Block = batch + complementary strip pair (qt, 31-qt): static load balance.
// 8 waves, each owns a 64-wide k-span per 512-col sweep; K fragments loaded
// global->reg (L2-hot, no LDS, no barriers in the K loop). Q broadcast via LDS
// (hi/lo bf16 split). MFMA swapped (A=K, B=Q): lane's f32x4 = 4 consecutive k
// of one q row -> 4 consecutive dwordx4 stores per row per sweep.
__global__ __launch_bounds__(512, 1)
void monotonic_attn(const float* __restrict__ Qg, const float* __restrict__ Kg,
                    float* __restrict__ out)
{
    __shared__ unsigned short qlds[8192];   // Q hi [0,4096), lo [4096,8192)
    __shared__ float red[8][64];

    // XCD-chunk swizzle (grid=256, %8==0 -> bijective): 2 batches per XCD
    const int bid  = blockIdx.x;
    const int wid  = (bid & 7) * ((int)gridDim.x >> 3) + (bid >> 3);
    const int b    = wid >> 4;
    const int pair = wid & 15;

    const int tid = threadIdx.x, lane = tid & 63, wv = tid >> 6;
    const int l15 = lane & 15, g = lane >> 4;

    const float* __restrict__ Qb = Qg + (size_t)b * S * D;
    const float* __restrict__ Kb = Kg + (size_t)b * S * D;
    float* __restrict__ outb = out + (size_t)b * (size_t)S * S;

    for (int half = 0; half < 2; ++half) {
        const int qt   = half ? pair : 31 - pair;
        const int q0   = qt * TQ;
        const int qmax = q0 + 63;
        const int NSW  = (q0 + TQ + 511) >> 9;   // 512-col sweeps

        // ---------------- stage Q (scaled, hi+lo, XOR-swizzled) ----------------
        {
            const int qrow = tid >> 3, qcp = tid & 7;
            const float4* src = reinterpret_cast<const float4*>(Qb + (size_t)(q0 + qrow) * D + qcp * 8);
            const float4 f0 = src[0], f1 = src[1];
            float v[8];
            *reinterpret_cast<float4*>(&v[0]) = f0;
            *reinterpret_cast<float4*>(&v[4]) = f1;
            u16x8 hv, lv;
            #pragma unroll
            for (int i = 0; i < 8; ++i) {
                const float s = v[i] * QSCALE;
                const unsigned short hb = bf16_rne(s);
                hv[i] = hb;
                lv[i] = bf16_rne(s - bf16_f32(hb));
            }
            const int off = qrow * 64 + (qcp ^ (qrow & 7)) * 8;
            *reinterpret_cast<u16x8*>(&qlds[off])        = hv;
            *reinterpret_cast<u16x8*>(&qlds[4096 + off]) = lv;
        }
        __syncthreads();                        // B1: Q staged before frag reads

        bf16x8 qhi[4][2], qlo[4][2];
        #pragma unroll
        for (int qs = 0; qs < 4; ++qs) {
            const int row = qs * 16 + l15;
            #pragma unroll
            for (int c = 0; c < 2; ++c) {
                const int off = row * 64 + ((((c << 2) | g)) ^ (row & 7)) * 8;
                qhi[qs][c] = *reinterpret_cast<const bf16x8*>(&qlds[off]);
                qlo[qs][c] = *reinterpret_cast<const bf16x8*>(&qlds[4096 + off]);
            }
        }

        // ---------------- pass A: row sums of exp (barrier-free) ----------------
        float rsum[4] = {0.f, 0.f, 0.f, 0.f};
        for (int sw = 0; sw < NSW; ++sw) {
            const int kb0 = sw * 512 + wv * 64;
            if (kb0 > qmax) continue;           // wave fully masked this sweep
            bf16x8 af[4][2];
            #pragma unroll
            for (int s2 = 0; s2 < 4; ++s2) {
                if (kb0 + s2 * 16 > qmax) continue;
                const float* rp = Kb + (size_t)(kb0 + s2 * 16 + l15) * D + g * 8;
                af[s2][0] = cvt8(*reinterpret_cast<const float4*>(rp),
                                 *reinterpret_cast<const float4*>(rp + 4));
                af[s2][1] = cvt8(*reinterpret_cast<const float4*>(rp + 32),
                                 *reinterpret_cast<const float4*>(rp + 36));
            }
            #pragma unroll
            for (int qs = 0; qs < 4; ++qs) {
                const int qmin = q0 + qs * 16, qg = qmin + l15;
                #pragma unroll
                for (int s2 = 0; s2 < 4; ++s2) {
                    const int klo = kb0 + s2 * 16;
                    if (klo > qmin + 15) continue;
                    f32x4 acc = {0.f, 0.f, 0.f, 0.f};
                    acc = mfma16(af[s2][0], qhi[qs][0], acc);
                    acc = mfma16(af[s2][1], qhi[qs][1], acc);
                    acc = mfma16(af[s2][0], qlo[qs][0], acc);
                    acc = mfma16(af[s2][1], qlo[qs][1], acc);
                    if (klo + 15 <= qmin) {
                        rsum[qs] += exp2f(acc[0]) + exp2f(acc[1]) + exp2f(acc[2]) + exp2f(acc[3]);
                    } else {
                        const int kb = klo + g * 4;
                        #pragma unroll
                        for (int r = 0; r < 4; ++r)
                            rsum[qs] += (kb + r <= qg) ? exp2f(acc[r]) : 0.f;
                    }
                }
            }
        }
        #pragma unroll
        for (int qs = 0; qs < 4; ++qs) {
            float v = rsum[qs];
            v += __shfl_xor(v, 16);
            v += __shfl_xor(v, 32);
            if (g == 0) red[wv][qs * 16 + l15] = v;
        }
        __syncthreads();                        // B2: sums visible
        float inv4[4];
        #pragma unroll
        for (int qs = 0; qs < 4; ++qs) {
            const int qi = qs * 16 + l15;
            inv4[qs] = 1.f / (red[0][qi] + red[1][qi] + red[2][qi] + red[3][qi]
                            + red[4][qi] + red[5][qi] + red[6][qi] + red[7][qi]);
        }

        // ---------------- pass B: recompute, normalize, store (barrier-free) ----------------
        for (int sw = 0; sw < NSW; ++sw) {
            const int kb0 = sw * 512 + wv * 64;
            const bool vis = (kb0 <= qmax);
            bf16x8 af[4][2];
            if (vis) {
                #pragma unroll
                for (int s2 = 0; s2 < 4; ++s2) {
                    if (kb0 + s2 * 16 > qmax) continue;
                    const float* rp = Kb + (size_t)(kb0 + s2 * 16 + l15) * D + g * 8;
                    af[s2][0] = cvt8(*reinterpret_cast<const float4*>(rp),
                                     *reinterpret_cast<const float4*>(rp + 4));
                    af[s2][1] = cvt8(*reinterpret_cast<const float4*>(rp + 32),
                                     *reinterpret_cast<const float4*>(rp + 36));
                }
            }
            #pragma unroll
            for (int qs = 0; qs < 4; ++qs) {
                const int qmin = q0 + qs * 16, qg = qmin + l15;
                float* rowp = outb + (size_t)qg * S + kb0 + g * 4;
                #pragma unroll
                for (int s2 = 0; s2 < 4; ++s2) {
                    const int klo = kb0 + s2 * 16;
                    f32x4 ov = {0.f, 0.f, 0.f, 0.f};
                    if (vis && klo <= qmin + 15) {
                        f32x4 acc = {0.f, 0.f, 0.f, 0.f};
                        acc = mfma16(af[s2][0], qhi[qs][0], acc);
                        acc = mfma16(af[s2][1], qhi[qs][1], acc);
                        acc = mfma16(af[s2][0], qlo[qs][0], acc);
                        acc = mfma16(af[s2][1], qlo[qs][1], acc);
                        if (klo + 15 <= qmin) {
                            ov[0] = exp2f(acc[0]) * inv4[qs];
                            ov[1] = exp2f(acc[1]) * inv4[qs];
                            ov[2] = exp2f(acc[2]) * inv4[qs];
                            ov[3] = exp2f(acc[3]) * inv4[qs];
                        } else {
                            const int kb = klo + g * 4;
                            ov[0] = (kb + 0 <= qg) ? exp2f(acc[0]) * inv4[qs] : 0.f;
                            ov[1] = (kb + 1 <= qg) ? exp2f(acc[1]) * inv4[qs] : 0.f;
                            ov[2] = (kb + 2 <= qg) ? exp2f(acc[2]) * inv4[qs] : 0.f;
                            ov[3] = (kb + 3 <= qg) ? exp2f(acc[3]) * inv4[qs] : 0.f;
                        }
                    }
                    __builtin_nontemporal_store(ov, reinterpret_cast<f32x4*>(rowp + s2 * 16));
                }
            }
        }

        // ---------------- zero-fill cols >= NSW*512 ----------------
        {
            const int c0 = NSW * 512;
            const f32x4 z = {0.f, 0.f, 0.f, 0.f};
            const size_t rb = (size_t)(q0 + (tid >> 3)) * S;
            for (int cc = c0 + (tid & 7) * 4; cc < S; cc += 32)
                __builtin_nontemporal_store(z, reinterpret_cast<f32x4*>(&outb[rb + cc]));
        }
        // next strip's Q staging is fenced by B2 of this strip (all frag reads
        // happened before pass A; every wave is past B2 before any wave can
        // reach the next strip's staging writes).
    }
}

extern "C" void kernel_launch(void* const* d_in, const int* in_sizes, int n_in,
                              void* d_out, int out_size, void* d_ws, size_t ws_size,
                              hipStream_t stream)
{
    const float* Q = (const float*)d_in[0];
    const float* K = (const float*)d_in[1];
    float* out     = (float*)d_out;
    const int nb   = in_sizes[0] / (S * D);   // 16 batches

    monotonic_attn<<<dim3(nb * 16), dim3(512), 0, stream>>>(Q, K, out);
}

// Round 6
// 93.070 us; speedup vs baseline: 1.2340x; 1.2340x over previous
//
#include <hip/hip_runtime.h>

using bf16x8 = __attribute__((ext_vector_type(8))) short;
using u16x8  = __attribute__((ext_vector_type(8))) unsigned short;
using f32x4  = __attribute__((ext_vector_type(4))) float;

static constexpr int S  = 2048;
static constexpr int D  = 64;
static constexpr int TQ = 64;
static constexpr int TK = 128;
static constexpr float QSCALE = 0.18033688f; // log2(e)/8 : exp2(dot) == exp(dot/8)

__device__ __forceinline__ unsigned short bf16_rne(float x) {
    unsigned u = __builtin_bit_cast(unsigned, x);
    u += 0x7FFFu + ((u >> 16) & 1u);
    return (unsigned short)(u >> 16);
}
__device__ __forceinline__ float bf16_f32(unsigned short h) {
    unsigned u = ((unsigned)h) << 16;
    return __builtin_bit_cast(float, u);
}
__device__ __forceinline__ f32x4 mfma16(bf16x8 a, bf16x8 b, f32x4 c) {
    return __builtin_amdgcn_mfma_f32_16x16x32_bf16(a, b, c, 0, 0, 0);
}
// Light barrier: LDS-visibility only. Does NOT drain vmcnt -> global stores
// stay fire-and-forget and K prefetch loads stay in flight across the barrier.
__device__ __forceinline__ void lbar() {
    asm volatile("s_waitcnt lgkmcnt(0)" ::: "memory");
    __builtin_amdgcn_s_barrier();
    asm volatile("" ::: "memory");
}

// One block = one batch + one COMPLEMENTARY strip pair (qt, 31-qt): exactly 17
// K-tiles per pass per block -> perfect static load balance. 8 waves; wave wv
// owns 16 k-cols of each 128-col K tile and all 64 q rows (Q hi/lo in regs).
// MFMA swapped (A=K, B=Q): lane's 4 acc values = 4 consecutive k of one q row.
__global__ __launch_bounds__(512, 1)
void monotonic_attn_mfma(const float* __restrict__ Qg,
                         const float* __restrict__ Kg,
                         float* __restrict__ out)
{
    __shared__ unsigned short lds[8192];   // 16 KB: Q stage hi[0,4096) lo[4096,8192); K stage [0,8192)
    __shared__ float red[8][64];

    // XCD-chunk swizzle (grid % 8 == 0): 2 batches per XCD
    const int bid  = blockIdx.x;
    const int wid  = (bid & 7) * ((int)gridDim.x >> 3) + (bid >> 3);
    const int b    = wid >> 4;
    const int pair = wid & 15;

    const int tid  = threadIdx.x;
    const int lane = tid & 63;
    const int wv   = tid >> 6;             // 0..7 : k-subtile owner
    const int l15  = lane & 15;
    const int g    = lane >> 4;

    const float* __restrict__ Qb = Qg + (size_t)b * S * D;
    const float* __restrict__ Kb = Kg + (size_t)b * S * D;
    float* __restrict__ outb = out + (size_t)b * (size_t)S * S;

    const int srow = tid >> 2;             // K staging: row 0..127
    const int scp  = tid & 3;              // 16-float chunk pair
    const int qrow = tid >> 3;             // Q staging: row 0..63
    const int qcp  = tid & 7;              // 8-float chunk

    // K fragment LDS offsets (constant across tiles)
    const int krow  = wv * 16 + l15;
    const int koff0 = krow * 64 + ((g)     ^ (krow & 7)) * 8;
    const int koff1 = krow * 64 + ((4 | g) ^ (krow & 7)) * 8;

    float4 pfa, pfb, pfc, pfd;             // register prefetch of next K tile

    for (int half = 0; half < 2; ++half) {
        const int qt = half ? pair : (31 - pair);
        const int q0 = qt * TQ;
        const int nt = (qt + 2) >> 1;      // ceil((q0+64)/128) K tiles

        // ---------------- stage Q (scaled, hi+lo planes, XOR-swizzled) ----------------
        lbar();                            // previous strip's LDS reads done
        {
            const float4* src = reinterpret_cast<const float4*>(Qb + (size_t)(q0 + qrow) * D + qcp * 8);
            const float4 f0 = src[0], f1 = src[1];
            float v[8];
            *reinterpret_cast<float4*>(&v[0]) = f0;
            *reinterpret_cast<float4*>(&v[4]) = f1;
            u16x8 hv, lv;
            #pragma unroll
            for (int i = 0; i < 8; ++i) {
                const float s = v[i] * QSCALE;
                const unsigned short hb = bf16_rne(s);
                hv[i] = hb;
                lv[i] = bf16_rne(s - bf16_f32(hb));
            }
            const int off = qrow * 64 + (qcp ^ (qrow & 7)) * 8;
            *reinterpret_cast<u16x8*>(&lds[off])        = hv;
            *reinterpret_cast<u16x8*>(&lds[4096 + off]) = lv;
        }
        lbar();                            // Q staged before frag reads

        // ---------------- Q fragments -> registers ----------------
        bf16x8 qhi[4][2], qlo[4][2];
        #pragma unroll
        for (int qs = 0; qs < 4; ++qs) {
            const int row = qs * 16 + l15;
            #pragma unroll
            for (int c = 0; c < 2; ++c) {
                const int off = row * 64 + (((c << 2) | g) ^ (row & 7)) * 8;
                qhi[qs][c] = *reinterpret_cast<const bf16x8*>(&lds[off]);
                qlo[qs][c] = *reinterpret_cast<const bf16x8*>(&lds[4096 + off]);
            }
        }

        float inv4[4];
        for (int pass = 0; pass < 2; ++pass) {
            float rsum[4] = {0.f, 0.f, 0.f, 0.f};
            {   // prefetch tile 0
                const float4* src = reinterpret_cast<const float4*>(Kb + (size_t)srow * D + scp * 16);
                pfa = src[0]; pfb = src[1]; pfc = src[2]; pfd = src[3];
            }
            for (int t = 0; t < nt; ++t) {
                const int k0 = t * TK;
                lbar();                    // WAR: all waves' reads of prev tile done
                {   // write staged K tile (bf16, XOR-swizzled)
                    float v[16];
                    *reinterpret_cast<float4*>(&v[0])  = pfa;
                    *reinterpret_cast<float4*>(&v[4])  = pfb;
                    *reinterpret_cast<float4*>(&v[8])  = pfc;
                    *reinterpret_cast<float4*>(&v[12]) = pfd;
                    #pragma unroll
                    for (int c2 = 0; c2 < 2; ++c2) {
                        u16x8 hv;
                        #pragma unroll
                        for (int i = 0; i < 8; ++i) hv[i] = bf16_rne(v[c2 * 8 + i]);
                        const int off = srow * 64 + (((scp << 1) | c2) ^ (srow & 7)) * 8;
                        *reinterpret_cast<u16x8*>(&lds[off]) = hv;
                    }
                }
                if (t + 1 < nt) {          // issue next-tile prefetch BEFORE the RAW
                    const float4* src = reinterpret_cast<const float4*>(Kb + (size_t)(k0 + TK + srow) * D + scp * 16);
                    pfa = src[0]; pfb = src[1]; pfc = src[2]; pfd = src[3];
                }
                lbar();                    // RAW: staged tile visible
                const bf16x8 kf0 = *reinterpret_cast<const bf16x8*>(&lds[koff0]);
                const bf16x8 kf1 = *reinterpret_cast<const bf16x8*>(&lds[koff1]);
                const int klo = k0 + wv * 16;
                const int kb  = klo + g * 4;
                #pragma unroll
                for (int qs = 0; qs < 4; ++qs) {
                    const int qmin = q0 + qs * 16;
                    const int qg   = qmin + l15;
                    if (pass == 0) {
                        if (klo > qmin + 15) continue;       // fully masked k-sub
                        f32x4 acc = {0.f, 0.f, 0.f, 0.f};
                        acc = mfma16(kf0, qhi[qs][0], acc);
                        acc = mfma16(kf1, qhi[qs][1], acc);
                        acc = mfma16(kf0, qlo[qs][0], acc);
                        acc = mfma16(kf1, qlo[qs][1], acc);
                        if (klo + 15 <= qmin) {
                            rsum[qs] += exp2f(acc[0]) + exp2f(acc[1]) + exp2f(acc[2]) + exp2f(acc[3]);
                        } else {
                            #pragma unroll
                            for (int r = 0; r < 4; ++r)
                                rsum[qs] += (kb + r <= qg) ? exp2f(acc[r]) : 0.f;
                        }
                    } else {
                        float4 ov; ov.x = 0.f; ov.y = 0.f; ov.z = 0.f; ov.w = 0.f;
                        if (klo <= qmin + 15) {
                            f32x4 acc = {0.f, 0.f, 0.f, 0.f};
                            acc = mfma16(kf0, qhi[qs][0], acc);
                            acc = mfma16(kf1, qhi[qs][1], acc);
                            acc = mfma16(kf0, qlo[qs][0], acc);
                            acc = mfma16(kf1, qlo[qs][1], acc);
                            if (klo + 15 <= qmin) {
                                ov.x = exp2f(acc[0]) * inv4[qs];
                                ov.y = exp2f(acc[1]) * inv4[qs];
                                ov.z = exp2f(acc[2]) * inv4[qs];
                                ov.w = exp2f(acc[3]) * inv4[qs];
                            } else {
                                ov.x = (kb + 0 <= qg) ? exp2f(acc[0]) * inv4[qs] : 0.f;
                                ov.y = (kb + 1 <= qg) ? exp2f(acc[1]) * inv4[qs] : 0.f;
                                ov.z = (kb + 2 <= qg) ? exp2f(acc[2]) * inv4[qs] : 0.f;
                                ov.w = (kb + 3 <= qg) ? exp2f(acc[3]) * inv4[qs] : 0.f;
                            }
                        }
                        *reinterpret_cast<float4*>(&outb[(size_t)qg * S + kb]) = ov;
                    }
                }
            }
            if (pass == 0) {               // cross-wave row-sum reduction
                #pragma unroll
                for (int qs = 0; qs < 4; ++qs) {
                    float v = rsum[qs];
                    v += __shfl_xor(v, 16);
                    v += __shfl_xor(v, 32);
                    if (g == 0) red[wv][qs * 16 + l15] = v;
                }
                lbar();                    // sums visible
                #pragma unroll
                for (int qs = 0; qs < 4; ++qs) {
                    const int qi = qs * 16 + l15;
                    inv4[qs] = 1.f / (red[0][qi] + red[1][qi] + red[2][qi] + red[3][qi]
                                    + red[4][qi] + red[5][qi] + red[6][qi] + red[7][qi]);
                }
            }
        }

        // ---------------- zero-fill columns >= nt*TK ----------------
        {
            const int c0 = nt * TK;
            float4 z; z.x = 0.f; z.y = 0.f; z.z = 0.f; z.w = 0.f;
            const size_t rb = (size_t)(q0 + (tid >> 3)) * S;
            for (int cc = c0 + (tid & 7) * 4; cc < S; cc += 32)
                *reinterpret_cast<float4*>(&outb[rb + cc]) = z;
        }
    }
}

extern "C" void kernel_launch(void* const* d_in, const int* in_sizes, int n_in,
                              void* d_out, int out_size, void* d_ws, size_t ws_size,
                              hipStream_t stream)
{
    const float* Q = (const float*)d_in[0];
    const float* K = (const float*)d_in[1];
    float* out     = (float*)d_out;
    const int nb   = in_sizes[0] / (S * D);   // batches (16)

    monotonic_attn_mfma<<<dim3(nb * 16), dim3(512), 0, stream>>>(Q, K, out);
}

// Round 7
// 67.428 us; speedup vs baseline: 1.7033x; 1.3803x over previous
//
#include <hip/hip_runtime.h>

using bf16x8 = __attribute__((ext_vector_type(8))) short;
using u16x8  = __attribute__((ext_vector_type(8))) unsigned short;
using f32x4  = __attribute__((ext_vector_type(4))) float;

static constexpr int S  = 2048;
static constexpr int D  = 64;
static constexpr int TQ = 64;
static constexpr float QSCALE = 0.18033688f; // log2(e)/8 : exp2(dot) == exp(dot/8)

__device__ __forceinline__ unsigned short bf16_rne(float x) {
    unsigned u = __builtin_bit_cast(unsigned, x);
    u += 0x7FFFu + ((u >> 16) & 1u);
    return (unsigned short)(u >> 16);
}
__device__ __forceinline__ float bf16_f32(unsigned short h) {
    unsigned u = ((unsigned)h) << 16;
    return __builtin_bit_cast(float, u);
}
__device__ __forceinline__ f32x4 mfma16(bf16x8 a, bf16x8 b, f32x4 c) {
    return __builtin_amdgcn_mfma_f32_16x16x32_bf16(a, b, c, 0, 0, 0);
}
// LDS-visibility barrier only: does NOT drain vmcnt (stores/prefetch stay in flight)
__device__ __forceinline__ void lbar() {
    asm volatile("s_waitcnt lgkmcnt(0)" ::: "memory");
    __builtin_amdgcn_s_barrier();
    asm volatile("" ::: "memory");
}

// Block = batch + complementary strip pair (qt, 31-qt). 8 waves, FULLY DECOUPLED
// in the K loop: wave wv owns k-chunks c ≡ wv (mod 8) (16 k-rows each), stages its
// own chunk into a private double-buffered LDS slot (coalesced 64 B/lane loads of a
// contiguous 4 KB span), depth-2 register prefetch. No block barriers except Q stage
// and the row-sum reduction (6 per block total). MFMA swapped (A=K, B=Q): lane's
// f32x4 = 4 consecutive k of one q row -> float4 stores.
__global__ __launch_bounds__(512, 1)
void monotonic_attn(const float* __restrict__ Qg, const float* __restrict__ Kg,
                    float* __restrict__ out)
{
    __shared__ unsigned short qlds[8192];        // Q hi [0,4096), lo [4096,8192)
    __shared__ unsigned short kls[8][2][1024];   // per-wave dbuf: 16 rows x 64 bf16
    __shared__ float red[8][64];

    // XCD-chunk swizzle (grid=256, %8==0 -> bijective): 2 batches per XCD
    const int bid  = blockIdx.x;
    const int wid  = (bid & 7) * ((int)gridDim.x >> 3) + (bid >> 3);
    const int b    = wid >> 4;
    const int pair = wid & 15;

    const int tid = threadIdx.x, lane = tid & 63, wv = tid >> 6;
    const int l15 = lane & 15, g = lane >> 4;

    const float* __restrict__ Qb = Qg + (size_t)b * S * D;
    const float* __restrict__ Kb = Kg + (size_t)b * S * D;
    float* __restrict__ outb = out + (size_t)b * (size_t)S * S;

    // K staging geometry (per wave): lane covers 16 floats of the 1024-float chunk
    const int srow  = lane >> 2;                 // row 0..15 within chunk
    const int scp   = lane & 3;                  // 16-float group -> 2 8-short chunks
    const int woff0 = srow * 64 + (((scp << 1)    ) ^ (srow & 7)) * 8;
    const int woff1 = srow * 64 + (((scp << 1) | 1) ^ (srow & 7)) * 8;
    const int roff0 = l15 * 64 + ((g    ) ^ (l15 & 7)) * 8;    // d-cols [8g,8g+8)
    const int roff1 = l15 * 64 + ((4 | g) ^ (l15 & 7)) * 8;    // d-cols [32+8g,+8)

    for (int half = 0; half < 2; ++half) {
        const int qt   = half ? pair : 31 - pair;
        const int q0   = qt * TQ;
        const int kend = q0 + TQ;
        const int nC   = kend >> 4;              // 16-row K chunks in [0,kend)
        const int ni   = (nC - wv + 7) >> 3;     // this wave's chunk count

        // ---------------- stage Q (scaled, hi+lo, XOR-swizzled) ----------------
        lbar();                                  // all waves done with prev strip
        {
            const int qrow = tid >> 3, qcp = tid & 7;
            const float4* src = reinterpret_cast<const float4*>(Qb + (size_t)(q0 + qrow) * D + qcp * 8);
            const float4 f0 = src[0], f1 = src[1];
            float v[8];
            *reinterpret_cast<float4*>(&v[0]) = f0;
            *reinterpret_cast<float4*>(&v[4]) = f1;
            u16x8 hv, lv;
            #pragma unroll
            for (int i = 0; i < 8; ++i) {
                const float s = v[i] * QSCALE;
                const unsigned short hb = bf16_rne(s);
                hv[i] = hb;
                lv[i] = bf16_rne(s - bf16_f32(hb));
            }
            const int off = qrow * 64 + (qcp ^ (qrow & 7)) * 8;
            *reinterpret_cast<u16x8*>(&qlds[off])        = hv;
            *reinterpret_cast<u16x8*>(&qlds[4096 + off]) = lv;
        }
        lbar();                                  // Q staged before frag reads

        bf16x8 qhi[4][2], qlo[4][2];
        #pragma unroll
        for (int qs = 0; qs < 4; ++qs) {
            const int row = qs * 16 + l15;
            #pragma unroll
            for (int c = 0; c < 2; ++c) {
                const int off = row * 64 + ((((c << 2) | g)) ^ (row & 7)) * 8;
                qhi[qs][c] = *reinterpret_cast<const bf16x8*>(&qlds[off]);
                qlo[qs][c] = *reinterpret_cast<const bf16x8*>(&qlds[4096 + off]);
            }
        }

        float inv4[4];
        for (int pass = 0; pass < 2; ++pass) {
            float rsum[4] = {0.f, 0.f, 0.f, 0.f};

            float4 ra0, ra1, ra2, ra3, rb0, rb1, rb2, rb3;   // two named reg sets
            auto issueA = [&](int i) {
                const int c = wv + (i << 3);
                const float4* p4 = reinterpret_cast<const float4*>(Kb) + (c << 8) + (lane << 2);
                ra0 = p4[0]; ra1 = p4[1]; ra2 = p4[2]; ra3 = p4[3];
            };
            auto issueB = [&](int i) {
                const int c = wv + (i << 3);
                const float4* p4 = reinterpret_cast<const float4*>(Kb) + (c << 8) + (lane << 2);
                rb0 = p4[0]; rb1 = p4[1]; rb2 = p4[2]; rb3 = p4[3];
            };
            auto stage = [&](int i, const float4& x0, const float4& x1,
                             const float4& x2, const float4& x3) {
                float v[16];
                *reinterpret_cast<float4*>(&v[0])  = x0;
                *reinterpret_cast<float4*>(&v[4])  = x1;
                *reinterpret_cast<float4*>(&v[8])  = x2;
                *reinterpret_cast<float4*>(&v[12]) = x3;
                u16x8 h0, h1;
                #pragma unroll
                for (int j = 0; j < 8; ++j) {
                    h0[j] = bf16_rne(v[j]);
                    h1[j] = bf16_rne(v[8 + j]);
                }
                unsigned short* bp = &kls[wv][i & 1][0];
                *reinterpret_cast<u16x8*>(&bp[woff0]) = h0;
                *reinterpret_cast<u16x8*>(&bp[woff1]) = h1;
            };
            auto comp = [&](int i) {
                const unsigned short* bp = &kls[wv][i & 1][0];
                const bf16x8 kf0 = *reinterpret_cast<const bf16x8*>(&bp[roff0]);
                const bf16x8 kf1 = *reinterpret_cast<const bf16x8*>(&bp[roff1]);
                const int klo = (wv + (i << 3)) << 4;
                const int kb  = klo + g * 4;
                #pragma unroll
                for (int qs = 0; qs < 4; ++qs) {
                    const int qmin = q0 + qs * 16, qg = qmin + l15;
                    if (pass == 0) {
                        if (klo > qmin + 15) continue;
                        f32x4 acc = {0.f, 0.f, 0.f, 0.f};
                        acc = mfma16(kf0, qhi[qs][0], acc);
                        acc = mfma16(kf1, qhi[qs][1], acc);
                        acc = mfma16(kf0, qlo[qs][0], acc);
                        acc = mfma16(kf1, qlo[qs][1], acc);
                        if (klo + 15 <= qmin) {
                            rsum[qs] += exp2f(acc[0]) + exp2f(acc[1]) + exp2f(acc[2]) + exp2f(acc[3]);
                        } else {
                            #pragma unroll
                            for (int r = 0; r < 4; ++r)
                                rsum[qs] += (kb + r <= qg) ? exp2f(acc[r]) : 0.f;
                        }
                    } else {
                        f32x4 ov = {0.f, 0.f, 0.f, 0.f};
                        if (klo <= qmin + 15) {
                            f32x4 acc = {0.f, 0.f, 0.f, 0.f};
                            acc = mfma16(kf0, qhi[qs][0], acc);
                            acc = mfma16(kf1, qhi[qs][1], acc);
                            acc = mfma16(kf0, qlo[qs][0], acc);
                            acc = mfma16(kf1, qlo[qs][1], acc);
                            if (klo + 15 <= qmin) {
                                ov[0] = exp2f(acc[0]) * inv4[qs];
                                ov[1] = exp2f(acc[1]) * inv4[qs];
                                ov[2] = exp2f(acc[2]) * inv4[qs];
                                ov[3] = exp2f(acc[3]) * inv4[qs];
                            } else {
                                ov[0] = (kb + 0 <= qg) ? exp2f(acc[0]) * inv4[qs] : 0.f;
                                ov[1] = (kb + 1 <= qg) ? exp2f(acc[1]) * inv4[qs] : 0.f;
                                ov[2] = (kb + 2 <= qg) ? exp2f(acc[2]) * inv4[qs] : 0.f;
                                ov[3] = (kb + 3 <= qg) ? exp2f(acc[3]) * inv4[qs] : 0.f;
                            }
                        }
                        *reinterpret_cast<f32x4*>(outb + (size_t)qg * S + kb) = ov;
                    }
                }
            };

            // per-wave pipeline, depth-2 prefetch, even/odd unrolled (static reg sets)
            if (ni > 0) issueA(0);
            if (ni > 1) issueB(1);
            int i = 0;
            for (; i + 2 <= ni; i += 2) {
                stage(i, ra0, ra1, ra2, ra3);
                if (i + 2 < ni) issueA(i + 2);
                comp(i);
                stage(i + 1, rb0, rb1, rb2, rb3);
                if (i + 3 < ni) issueB(i + 3);
                comp(i + 1);
            }
            if (i < ni) { stage(i, ra0, ra1, ra2, ra3); comp(i); }

            if (pass == 0) {                     // cross-wave row-sum reduction
                #pragma unroll
                for (int qs = 0; qs < 4; ++qs) {
                    float v = rsum[qs];
                    v += __shfl_xor(v, 16);
                    v += __shfl_xor(v, 32);
                    if (g == 0) red[wv][qs * 16 + l15] = v;
                }
                lbar();                          // sums visible
                #pragma unroll
                for (int qs = 0; qs < 4; ++qs) {
                    const int qi = qs * 16 + l15;
                    inv4[qs] = 1.f / (red[0][qi] + red[1][qi] + red[2][qi] + red[3][qi]
                                    + red[4][qi] + red[5][qi] + red[6][qi] + red[7][qi]);
                }
            }
        }

        // ---------------- zero-fill columns >= kend ----------------
        {
            f32x4 z = {0.f, 0.f, 0.f, 0.f};
            const size_t rb = (size_t)(q0 + (tid >> 3)) * S;
            for (int cc = kend + (tid & 7) * 4; cc < S; cc += 32)
                *reinterpret_cast<f32x4*>(&outb[rb + cc]) = z;
        }
    }
}

extern "C" void kernel_launch(void* const* d_in, const int* in_sizes, int n_in,
                              void* d_out, int out_size, void* d_ws, size_t ws_size,
                              hipStream_t stream)
{
    const float* Q = (const float*)d_in[0];
    const float* K = (const float*)d_in[1];
    float* out     = (float*)d_out;
    const int nb   = in_sizes[0] / (S * D);   // 16 batches

    monotonic_attn<<<dim3(nb * 16), dim3(512), 0, stream>>>(Q, K, out);
}